// Round 5
// baseline (70.985 us; speedup 1.0000x reference)
//
#include <hip/hip_runtime.h>
#include <math.h>

#define NGAMES 16384
#define BRD 64
#define CELLS 4096     // 64*64
#define THREADS 256    // 4 waves/block, one game per wave
#define GPB 4          // games per block
#define CHUNKS 16      // 16 float4 per lane; 64*16*4 = 4096 cells

typedef float f4 __attribute__((ext_vector_type(4)));

__global__ __launch_bounds__(THREADS) void snake_step_kernel(
    const float* __restrict__ state,
    const int*   __restrict__ pos_prev,
    const int*   __restrict__ pos_cur,
    const int*   __restrict__ action,
    const float* __restrict__ noise,
    float*       __restrict__ out)
{
    const int g    = blockIdx.x * GPB + (threadIdx.x >> 6);   // game id (one per wave)
    const int lane = threadIdx.x & 63;
    const float* sg = state + (size_t)g * CELLS;
    float*       og = out   + (size_t)g * CELLS;
    const f4* sg4 = reinterpret_cast<const f4*>(sg);
    f4*       og4 = reinterpret_cast<f4*>(og);

    // ---- bulk load FIRST (addresses depend only on g/lane -> issue immediately) ----
    f4 v[CHUNKS];
    #pragma unroll
    for (int k = 0; k < CHUNKS; ++k)
        v[k] = sg4[lane + k * 64];

    // ---- scalar per-game logic (wave-uniform; tiny loads overlap the bulk stream) ----
    const int pp0 = pos_prev[2 * g], pp1 = pos_prev[2 * g + 1];
    const int pc0 = pos_cur[2 * g],  pc1 = pos_cur[2 * g + 1];
    const int a = action[g];
    const int d0 = pc0 - pp0, d1 = pc1 - pp1;
    int nd0 = d0, nd1 = d1;
    if (a == 0)      { nd0 = -d1; nd1 =  d0; }   // left
    else if (a == 2) { nd0 =  d1; nd1 = -d0; }   // right
    int pn0 = pc0 + nd0, pn1 = pc1 + nd1;
    const bool outside = (pn0 < 0) | (pn0 >= BRD) | (pn1 < 0) | (pn1 >= BRD);
    pn0 = min(max(pn0, 0), BRD - 1);
    pn1 = min(max(pn1, 0), BRD - 1);
    const int posn_spec = pn0 * BRD + pn1;       // pos_next assuming !dead
    const int posc_live = pc0 * BRD + pc1;

    // wave-uniform broadcast loads (independent of bulk stream)
    const float cellv = sg[posn_spec];
    const float curv  = sg[posc_live];

    // ---- speculative transform: assume !dead && !feeding (decrement positives) ----
    #pragma unroll
    for (int k = 0; k < CHUNKS; ++k) {
        #pragma unroll
        for (int j = 0; j < 4; ++j)
            v[k][j] = (v[k][j] > 0.0f) ? v[k][j] - 1.0f : v[k][j];
    }

    const int  headF   = posn_spec >> 2;         // float4 index of head cell
    const int  headK   = headF >> 6;             // chunk of head cell
    const bool ownHead = (lane == (headF & 63));

    // ---- speculative stores: everything except the owner's head chunk ----
    #pragma unroll
    for (int k = 0; k < CHUNKS; ++k)
        if (!(ownHead && k == headK))
            __builtin_nontemporal_store(v[k], &og4[lane + k * 64]);

    // ---- resolve gates (stores above did NOT wait on these) ----
    const bool dead    = outside | (cellv > 0.0f);
    const bool feeding = (cellv == -1.0f);
    const bool rare    = dead | feeding;         // == spawn

    if (!rare) {
        // common path: owner merges head+1 into its deferred chunk and stores it
        if (ownHead) {
            const float headv = (curv > 0.0f) ? curv - 1.0f : curv;  // post-dec head
            const float hv = headv + 1.0f;
            const int j = posn_spec & 3;
            #pragma unroll
            for (int k = 0; k < CHUNKS; ++k)
                if (k == headK) {
                    f4 w = v[k];
                    w[j] = hv;
                    __builtin_nontemporal_store(w, &og4[lane + k * 64]);
                }
        }
        return;
    }

    // ========== rare path (dead or feeding; wave-uniform, NO barriers/LDS) ==========
    // reload original state into v (L2/L3-hot)
    #pragma unroll
    for (int k = 0; k < CHUNKS; ++k)
        v[k] = sg4[lane + k * 64];

    // dead: zero board, respawn (32,30)=1 (32,31)=2 (32,32)=1
    if (dead) {
        #pragma unroll
        for (int k = 0; k < CHUNKS; ++k) {
            #pragma unroll
            for (int j = 0; j < 4; ++j) {
                const int idx = (lane + k * 64) * 4 + j;
                float x = 0.0f;
                if (idx == 2078) x = 1.0f;
                else if (idx == 2079) x = 2.0f;
                else if (idx == 2080) x = 1.0f;
                v[k][j] = x;
            }
        }
    }

    // spawn (== rare): argmax(noise) over empty cells — pure wave reduce
    int food;
    {
        float bv = -INFINITY;
        int   bi = 0x7FFFFFFF;
        const f4* ng4 = reinterpret_cast<const f4*>(noise + (size_t)g * CELLS);
        #pragma unroll
        for (int k = 0; k < CHUNKS; ++k) {
            const f4 nv = ng4[lane + k * 64];
            #pragma unroll
            for (int j = 0; j < 4; ++j) {
                const int idx = (lane + k * 64) * 4 + j;
                if (v[k][j] == 0.0f) {
                    const float n = nv[j];
                    if (n > bv || (n == bv && idx < bi)) { bv = n; bi = idx; }
                }
            }
        }
        #pragma unroll
        for (int off = 32; off > 0; off >>= 1) {
            const float ov = __shfl_xor(bv, off, 64);
            const int   oi = __shfl_xor(bi, off, 64);
            if (ov > bv || (ov == bv && oi < bi)) { bv = ov; bi = oi; }
        }
        food = (bv == -INFINITY) ? 0 : bi;       // all non-empty -> argmax = 0 (jnp)
    }

    // food placement + decrement
    #pragma unroll
    for (int k = 0; k < CHUNKS; ++k) {
        #pragma unroll
        for (int j = 0; j < 4; ++j) {
            const int idx = (lane + k * 64) * 4 + j;
            if (idx == food) v[k][j] = -1.0f;
            if (!feeding && v[k][j] > 0.0f) v[k][j] -= 1.0f;
        }
    }

    // head value (scalar, every lane computes the same)
    const int posc = dead ? (32 * BRD + 31) : posc_live;   // 2079
    const int posn = dead ? (32 * BRD + 32) : posn_spec;   // 2080
    float headv = dead ? 2.0f : curv;
    if (food == posc) headv = -1.0f;
    if (!feeding && headv > 0.0f) headv -= 1.0f;
    const float hv = headv + 1.0f;

    // full rewrite with head merged (every address rewritten by its original writer)
    const int posnF = posn >> 2, posnJ = posn & 3;
    #pragma unroll
    for (int k = 0; k < CHUNKS; ++k) {
        f4 w = v[k];
        if ((lane + k * 64) == posnF) w[posnJ] = hv;
        og4[lane + k * 64] = w;
    }
}

extern "C" void kernel_launch(void* const* d_in, const int* in_sizes, int n_in,
                              void* d_out, int out_size, void* d_ws, size_t ws_size,
                              hipStream_t stream) {
    const float* state    = (const float*)d_in[0];
    const int*   pos_prev = (const int*)d_in[1];
    const int*   pos_cur  = (const int*)d_in[2];
    const int*   action   = (const int*)d_in[3];
    const float* noise    = (const float*)d_in[4];
    float*       out      = (float*)d_out;

    snake_step_kernel<<<NGAMES / GPB, THREADS, 0, stream>>>(
        state, pos_prev, pos_cur, action, noise, out);
}

// Round 6
// 69.086 us; speedup vs baseline: 1.0275x; 1.0275x over previous
//
#include <hip/hip_runtime.h>
#include <math.h>

#define NGAMES 16384
#define BRD 64
#define CELLS 4096   // 64*64
#define THREADS 128
#define CHUNKS 8     // 8 float4 per thread; 128*8*4 = 4096 cells
#define NWAVES (THREADS / 64)

typedef float f4 __attribute__((ext_vector_type(4)));

// streaming store: non-temporal at ALL cache levels (sc1 = system scope, nt = non-temporal)
__device__ __forceinline__ void store_stream(f4* p, f4 v) {
    asm volatile("global_store_dwordx4 %0, %1, off sc1 nt" :: "v"(p), "v"(v) : "memory");
}

__global__ __launch_bounds__(THREADS) void snake_step_kernel(
    const float* __restrict__ state,
    const int*   __restrict__ pos_prev,
    const int*   __restrict__ pos_cur,
    const int*   __restrict__ action,
    const float* __restrict__ noise,
    float*       __restrict__ out)
{
    const int g = blockIdx.x;
    const int t = threadIdx.x;
    const float* sg = state + (size_t)g * CELLS;
    float*       og = out   + (size_t)g * CELLS;

    __shared__ float wv[NWAVES];
    __shared__ int   wi[NWAVES];
    __shared__ int   food_s;

    // ---- scalar per-game logic (pure int math after tiny loads) ----
    const int pp0 = pos_prev[2 * g], pp1 = pos_prev[2 * g + 1];
    const int pc0 = pos_cur[2 * g],  pc1 = pos_cur[2 * g + 1];
    const int a = action[g];
    const int d0 = pc0 - pp0, d1 = pc1 - pp1;
    int nd0 = d0, nd1 = d1;
    if (a == 0)      { nd0 = -d1; nd1 =  d0; }   // left
    else if (a == 2) { nd0 =  d1; nd1 = -d0; }   // right
    int pn0 = pc0 + nd0, pn1 = pc1 + nd1;
    const bool outside = (pn0 < 0) | (pn0 >= BRD) | (pn1 < 0) | (pn1 >= BRD);
    pn0 = min(max(pn0, 0), BRD - 1);
    pn1 = min(max(pn1, 0), BRD - 1);
    const int posn_spec = pn0 * BRD + pn1;       // pos_next assuming !dead
    const int posc_live = pc0 * BRD + pc1;

    // broadcast loads (in flight while bulk loads stream)
    const float cellv = sg[posn_spec];
    const float curv  = sg[posc_live];

    // ---- bulk load (independent of broadcasts) ----
    f4 v[CHUNKS];
    const f4* sg4 = reinterpret_cast<const f4*>(sg);
    #pragma unroll
    for (int k = 0; k < CHUNKS; ++k)
        v[k] = sg4[t + k * THREADS];

    // ---- speculative transform: assume !dead && !feeding (-> decrement positives) ----
    #pragma unroll
    for (int k = 0; k < CHUNKS; ++k) {
        #pragma unroll
        for (int j = 0; j < 4; ++j)
            v[k][j] = (v[k][j] > 0.0f) ? v[k][j] - 1.0f : v[k][j];
    }

    const int  headF   = posn_spec >> 2;            // float4 index of head cell
    const int  headK   = headF >> 7;                // = headF / THREADS
    const bool ownHead = (t == (headF & (THREADS - 1)));

    // ---- speculative streaming stores: everything except the owner's head chunk ----
    f4* og4 = reinterpret_cast<f4*>(og);
    #pragma unroll
    for (int k = 0; k < CHUNKS; ++k)
        if (!(ownHead && k == headK))
            store_stream(&og4[t + k * THREADS], v[k]);

    // ---- resolve gates (stores above did NOT wait on these) ----
    const bool dead    = outside | (cellv > 0.0f);
    const bool feeding = (cellv == -1.0f);
    const bool rare    = dead | feeding;            // == spawn

    if (!rare) {
        // common path: owner merges head+1 into its deferred chunk and stores it
        if (ownHead) {
            const float headv = (curv > 0.0f) ? curv - 1.0f : curv;  // post-dec head
            const float hv = headv + 1.0f;
            const int j = posn_spec & 3;
            #pragma unroll
            for (int k = 0; k < CHUNKS; ++k)
                if (k == headK) {
                    f4 w = v[k];
                    w[j] = hv;
                    store_stream(&og4[t + k * THREADS], w);
                }
        }
        return;
    }

    // ================= rare path (dead or feeding; block-uniform) =================
    __syncthreads();   // keep waves together before full rewrite

    // reload original state (L2-hot)
    float s[CHUNKS * 4];
    f4* s4 = reinterpret_cast<f4*>(s);
    #pragma unroll
    for (int k = 0; k < CHUNKS; ++k)
        s4[k] = sg4[t + k * THREADS];

    // dead: zero board, respawn (32,30)=1 (32,31)=2 (32,32)=1
    if (dead) {
        #pragma unroll
        for (int k = 0; k < CHUNKS; ++k) {
            #pragma unroll
            for (int j = 0; j < 4; ++j) {
                const int idx = (t + k * THREADS) * 4 + j;
                float x = 0.0f;
                if (idx == 2078) x = 1.0f;
                else if (idx == 2079) x = 2.0f;
                else if (idx == 2080) x = 1.0f;
                s[k * 4 + j] = x;
            }
        }
    }

    // spawn (== rare): argmax(noise) over empty cells
    {
        float bv = -INFINITY;
        int   bi = 0x7FFFFFFF;
        const f4* ng4 = reinterpret_cast<const f4*>(noise + (size_t)g * CELLS);
        #pragma unroll
        for (int k = 0; k < CHUNKS; ++k) {
            const f4 nv = ng4[t + k * THREADS];
            #pragma unroll
            for (int j = 0; j < 4; ++j) {
                const int idx = (t + k * THREADS) * 4 + j;
                if (s[k * 4 + j] == 0.0f) {
                    const float n = nv[j];
                    if (n > bv || (n == bv && idx < bi)) { bv = n; bi = idx; }
                }
            }
        }
        #pragma unroll
        for (int off = 32; off > 0; off >>= 1) {
            const float ov = __shfl_xor(bv, off, 64);
            const int   oi = __shfl_xor(bi, off, 64);
            if (ov > bv || (ov == bv && oi < bi)) { bv = ov; bi = oi; }
        }
        const int wave = t >> 6;
        if ((t & 63) == 0) { wv[wave] = bv; wi[wave] = bi; }
        __syncthreads();
        if (t == 0) {
            float fv = wv[0]; int fi = wi[0];
            #pragma unroll
            for (int w = 1; w < NWAVES; ++w)
                if (wv[w] > fv || (wv[w] == fv && wi[w] < fi)) { fv = wv[w]; fi = wi[w]; }
            food_s = (fv == -INFINITY) ? 0 : fi;   // all -inf -> argmax = 0 (jnp semantics)
        }
        __syncthreads();
    }
    const int food = food_s;

    // food placement + decrement
    #pragma unroll
    for (int k = 0; k < CHUNKS; ++k) {
        #pragma unroll
        for (int j = 0; j < 4; ++j) {
            const int idx = (t + k * THREADS) * 4 + j;
            if (idx == food) s[k * 4 + j] = -1.0f;
            if (!feeding && s[k * 4 + j] > 0.0f) s[k * 4 + j] -= 1.0f;
        }
    }

    // head value (scalar, every thread)
    const int posc = dead ? (32 * BRD + 31) : posc_live;   // 2079
    const int posn = dead ? (32 * BRD + 32) : posn_spec;   // 2080
    float headv = dead ? 2.0f : curv;
    if (food == posc) headv = -1.0f;
    if (!feeding && headv > 0.0f) headv -= 1.0f;
    const float hv = headv + 1.0f;

    // full rewrite with head merged (every address rewritten by its original writer)
    const int posnF = posn >> 2, posnJ = posn & 3;
    #pragma unroll
    for (int k = 0; k < CHUNKS; ++k) {
        f4 w = s4[k];
        if ((t + k * THREADS) == posnF) w[posnJ] = hv;
        og4[t + k * THREADS] = w;
    }
}

extern "C" void kernel_launch(void* const* d_in, const int* in_sizes, int n_in,
                              void* d_out, int out_size, void* d_ws, size_t ws_size,
                              hipStream_t stream) {
    const float* state    = (const float*)d_in[0];
    const int*   pos_prev = (const int*)d_in[1];
    const int*   pos_cur  = (const int*)d_in[2];
    const int*   action   = (const int*)d_in[3];
    const float* noise    = (const float*)d_in[4];
    float*       out      = (float*)d_out;

    snake_step_kernel<<<NGAMES, THREADS, 0, stream>>>(
        state, pos_prev, pos_cur, action, noise, out);
}

// Round 7
// 68.259 us; speedup vs baseline: 1.0399x; 1.0121x over previous
//
#include <hip/hip_runtime.h>
#include <math.h>

#define NGAMES 16384
#define BRD 64
#define CELLS 4096   // 64*64
#define THREADS 256
#define CHUNKS 4     // 4 float4 per thread; 256*4*4 = 4096 cells
#define NWAVES (THREADS / 64)

typedef float f4 __attribute__((ext_vector_type(4)));

// streaming store: non-temporal (no L2/L3 pollution where honored)
__device__ __forceinline__ void store_stream(f4* p, f4 v) {
    asm volatile("global_store_dwordx4 %0, %1, off sc1 nt" :: "v"(p), "v"(v) : "memory");
}

__global__ __launch_bounds__(THREADS) void snake_step_kernel(
    const float* __restrict__ state,
    const int*   __restrict__ pos_prev,
    const int*   __restrict__ pos_cur,
    const int*   __restrict__ action,
    const float* __restrict__ noise,
    float*       __restrict__ out)
{
    const int g = blockIdx.x;
    const int t = threadIdx.x;
    const float* sg = state + (size_t)g * CELLS;
    float*       og = out   + (size_t)g * CELLS;

    __shared__ float wv[NWAVES];
    __shared__ int   wi[NWAVES];
    __shared__ int   food_s;

    // ---- scalar per-game logic (pure int math after tiny loads) ----
    const int pp0 = pos_prev[2 * g], pp1 = pos_prev[2 * g + 1];
    const int pc0 = pos_cur[2 * g],  pc1 = pos_cur[2 * g + 1];
    const int a = action[g];
    const int d0 = pc0 - pp0, d1 = pc1 - pp1;
    int nd0 = d0, nd1 = d1;
    if (a == 0)      { nd0 = -d1; nd1 =  d0; }   // left
    else if (a == 2) { nd0 =  d1; nd1 = -d0; }   // right
    int pn0 = pc0 + nd0, pn1 = pc1 + nd1;
    const bool outside = (pn0 < 0) | (pn0 >= BRD) | (pn1 < 0) | (pn1 >= BRD);
    pn0 = min(max(pn0, 0), BRD - 1);
    pn1 = min(max(pn1, 0), BRD - 1);
    const int posn_spec = pn0 * BRD + pn1;       // pos_next assuming !dead
    const int posc_live = pc0 * BRD + pc1;

    // broadcast loads (in flight while bulk loads stream)
    const float cellv = sg[posn_spec];
    const float curv  = sg[posc_live];

    // ---- bulk load (independent of broadcasts) ----
    f4 v[CHUNKS];
    const f4* sg4 = reinterpret_cast<const f4*>(sg);
    #pragma unroll
    for (int k = 0; k < CHUNKS; ++k)
        v[k] = sg4[t + k * THREADS];

    // ---- speculative transform: assume !dead && !feeding (-> decrement positives) ----
    #pragma unroll
    for (int k = 0; k < CHUNKS; ++k) {
        #pragma unroll
        for (int j = 0; j < 4; ++j)
            v[k][j] = (v[k][j] > 0.0f) ? v[k][j] - 1.0f : v[k][j];
    }

    const int  headF   = posn_spec >> 2;            // float4 index of head cell
    const int  headK   = headF >> 8;                // = headF / THREADS
    const bool ownHead = (t == (headF & (THREADS - 1)));

    // ---- speculative streaming stores: everything except the owner's head chunk ----
    f4* og4 = reinterpret_cast<f4*>(og);
    #pragma unroll
    for (int k = 0; k < CHUNKS; ++k)
        if (!(ownHead && k == headK))
            store_stream(&og4[t + k * THREADS], v[k]);

    // ---- resolve gates (stores above did NOT wait on these) ----
    const bool dead    = outside | (cellv > 0.0f);
    const bool feeding = (cellv == -1.0f);
    const bool rare    = dead | feeding;            // == spawn

    if (!rare) {
        // common path: owner merges head+1 into its deferred chunk and stores it
        if (ownHead) {
            const float headv = (curv > 0.0f) ? curv - 1.0f : curv;  // post-dec head
            const float hv = headv + 1.0f;
            const int j = posn_spec & 3;
            #pragma unroll
            for (int k = 0; k < CHUNKS; ++k)
                if (k == headK) {
                    f4 w = v[k];
                    w[j] = hv;
                    store_stream(&og4[t + k * THREADS], w);
                }
        }
        return;
    }

    // ================= rare path (dead or feeding; block-uniform) =================
    __syncthreads();   // keep waves together before full rewrite

    // reload original state (L2-hot)
    float s[CHUNKS * 4];
    f4* s4 = reinterpret_cast<f4*>(s);
    #pragma unroll
    for (int k = 0; k < CHUNKS; ++k)
        s4[k] = sg4[t + k * THREADS];

    // dead: zero board, respawn (32,30)=1 (32,31)=2 (32,32)=1
    if (dead) {
        #pragma unroll
        for (int k = 0; k < CHUNKS; ++k) {
            #pragma unroll
            for (int j = 0; j < 4; ++j) {
                const int idx = (t + k * THREADS) * 4 + j;
                float x = 0.0f;
                if (idx == 2078) x = 1.0f;
                else if (idx == 2079) x = 2.0f;
                else if (idx == 2080) x = 1.0f;
                s[k * 4 + j] = x;
            }
        }
    }

    // spawn (== rare): argmax(noise) over empty cells
    {
        float bv = -INFINITY;
        int   bi = 0x7FFFFFFF;
        const f4* ng4 = reinterpret_cast<const f4*>(noise + (size_t)g * CELLS);
        #pragma unroll
        for (int k = 0; k < CHUNKS; ++k) {
            const f4 nv = ng4[t + k * THREADS];
            #pragma unroll
            for (int j = 0; j < 4; ++j) {
                const int idx = (t + k * THREADS) * 4 + j;
                if (s[k * 4 + j] == 0.0f) {
                    const float n = nv[j];
                    if (n > bv || (n == bv && idx < bi)) { bv = n; bi = idx; }
                }
            }
        }
        #pragma unroll
        for (int off = 32; off > 0; off >>= 1) {
            const float ov = __shfl_xor(bv, off, 64);
            const int   oi = __shfl_xor(bi, off, 64);
            if (ov > bv || (ov == bv && oi < bi)) { bv = ov; bi = oi; }
        }
        const int wave = t >> 6;
        if ((t & 63) == 0) { wv[wave] = bv; wi[wave] = bi; }
        __syncthreads();
        if (t == 0) {
            float fv = wv[0]; int fi = wi[0];
            #pragma unroll
            for (int w = 1; w < NWAVES; ++w)
                if (wv[w] > fv || (wv[w] == fv && wi[w] < fi)) { fv = wv[w]; fi = wi[w]; }
            food_s = (fv == -INFINITY) ? 0 : fi;   // all -inf -> argmax = 0 (jnp semantics)
        }
        __syncthreads();
    }
    const int food = food_s;

    // food placement + decrement
    #pragma unroll
    for (int k = 0; k < CHUNKS; ++k) {
        #pragma unroll
        for (int j = 0; j < 4; ++j) {
            const int idx = (t + k * THREADS) * 4 + j;
            if (idx == food) s[k * 4 + j] = -1.0f;
            if (!feeding && s[k * 4 + j] > 0.0f) s[k * 4 + j] -= 1.0f;
        }
    }

    // head value (scalar, every thread)
    const int posc = dead ? (32 * BRD + 31) : posc_live;   // 2079
    const int posn = dead ? (32 * BRD + 32) : posn_spec;   // 2080
    float headv = dead ? 2.0f : curv;
    if (food == posc) headv = -1.0f;
    if (!feeding && headv > 0.0f) headv -= 1.0f;
    const float hv = headv + 1.0f;

    // full rewrite with head merged (every address rewritten by its original writer)
    const int posnF = posn >> 2, posnJ = posn & 3;
    #pragma unroll
    for (int k = 0; k < CHUNKS; ++k) {
        f4 w = s4[k];
        if ((t + k * THREADS) == posnF) w[posnJ] = hv;
        og4[t + k * THREADS] = w;
    }
}

extern "C" void kernel_launch(void* const* d_in, const int* in_sizes, int n_in,
                              void* d_out, int out_size, void* d_ws, size_t ws_size,
                              hipStream_t stream) {
    const float* state    = (const float*)d_in[0];
    const int*   pos_prev = (const int*)d_in[1];
    const int*   pos_cur  = (const int*)d_in[2];
    const int*   action   = (const int*)d_in[3];
    const float* noise    = (const float*)d_in[4];
    float*       out      = (float*)d_out;

    snake_step_kernel<<<NGAMES, THREADS, 0, stream>>>(
        state, pos_prev, pos_cur, action, noise, out);
}